// Round 7
// baseline (10467.635 us; speedup 1.0000x reference)
//
#include <hip/hip_runtime.h>
#include <math.h>

// Problem constants
#define BB     32      // batch
#define KBM    5       // beam width
#define NR     160     // BB*KBM rows (beam-major)
#define HD     512     // hidden
#define TT     256     // encoder time steps
#define VV     5000    // vocab
#define MAXLEN 64
#define EOSID  2
#define NEGV   (-1e9f)
#define NEGBIG (-3.0e38f)
#define SCALEF 0.04419417382415922f  // 1/sqrt(512)
#define NBLK   256
#define NTHR   512
#define NBUF   32      // A_cat ring depth (power of 2); 1 fence at wrap

typedef float v4f __attribute__((ext_vector_type(4)));

// ---- coherent (L2-bypass) scalar ops for small mutable data ----
__device__ __forceinline__ float ld_sysf(const float* p) {
  return __hip_atomic_load(p, __ATOMIC_RELAXED, __HIP_MEMORY_SCOPE_SYSTEM);
}
__device__ __forceinline__ void st_sysf(float* p, float v) {
  __hip_atomic_store(p, v, __ATOMIC_RELAXED, __HIP_MEMORY_SCOPE_SYSTEM);
}
__device__ __forceinline__ int ld_sysi(const int* p) {
  return __hip_atomic_load(p, __ATOMIC_RELAXED, __HIP_MEMORY_SCOPE_SYSTEM);
}
__device__ __forceinline__ void st_sysi(int* p, int v) {
  __hip_atomic_store(p, v, __ATOMIC_RELAXED, __HIP_MEMORY_SCOPE_SYSTEM);
}

// ---- non-blocking issue + register-bound wait (issue-early / bind-late) ----
__device__ __forceinline__ v4f ld4_issue_sys(const float* p) {   // bypass, coherent
  v4f v;
  asm volatile("global_load_dwordx4 %0, %1, off sc0 sc1" : "=v"(v) : "v"(p));
  return v;
}
__device__ __forceinline__ v4f ld4_issue(const float* p) {       // cached
  v4f v;
  asm volatile("global_load_dwordx4 %0, %1, off" : "=v"(v) : "v"(p));
  return v;
}
__device__ __forceinline__ void vm_bind2(v4f& a, v4f& b) {
  asm volatile("s_waitcnt vmcnt(0)" : "+v"(a), "+v"(b) :: "memory");
}
__device__ __forceinline__ void vm_bind3(v4f& a, v4f& b, v4f& c) {
  asm volatile("s_waitcnt vmcnt(0)" : "+v"(a), "+v"(b), "+v"(c) :: "memory");
}
__device__ __forceinline__ void vm_bind4(v4f& a, v4f& b, v4f& c, v4f& d) {
  asm volatile("s_waitcnt vmcnt(0)" : "+v"(a), "+v"(b), "+v"(c), "+v"(d) :: "memory");
}
__device__ __forceinline__ void vm_bind5(v4f& a, v4f& b, v4f& c, v4f& d, v4f& e) {
  asm volatile("s_waitcnt vmcnt(0)"
               : "+v"(a), "+v"(b), "+v"(c), "+v"(d), "+v"(e) :: "memory");
}
__device__ __forceinline__ void st4_sys(float* p, v4f v) {
  asm volatile("global_store_dwordx4 %0, %1, off sc0 sc1" :: "v"(p), "v"(v) : "memory");
}

// comparator matching jax.lax.top_k stability: value desc, index asc on ties
__device__ __forceinline__ bool viBetter(float av, int ai, float bv, int bi) {
  return (av > bv) || (av == bv && ai < bi);
}

__device__ __forceinline__ void top5_insert(float tv[5], int ti[5], float x, int v) {
  if (!viBetter(x, v, tv[4], ti[4])) return;
  tv[4] = x; ti[4] = v;
#pragma unroll
  for (int q = 4; q > 0; q--) {
    if (viBetter(tv[q], ti[q], tv[q - 1], ti[q - 1])) {
      float tf = tv[q - 1]; int tx2 = ti[q - 1];
      tv[q - 1] = tv[q]; ti[q - 1] = ti[q];
      tv[q] = tf; ti[q] = tx2;
    } else break;
  }
}

template<int LEVELS>
__device__ __forceinline__ void bfly_argmax(float& v, int& i) {
#pragma unroll
  for (int d = 1; d < (1 << LEVELS); d <<= 1) {
    float ov = __shfl_xor(v, d);
    int oi = __shfl_xor(i, d);
    if (viBetter(ov, oi, v, i)) { v = ov; i = oi; }
  }
}

__global__ void k_zero(unsigned int* bar) {
  if (threadIdx.x < 320)
    __hip_atomic_store(&bar[threadIdx.x], 0u, __ATOMIC_RELAXED, __HIP_MEMORY_SCOPE_SYSTEM);
}

__launch_bounds__(NTHR, 1)
__global__ void k_persist(const int* __restrict__ input_var, const float* __restrict__ enc,
                          const float* __restrict__ emb, const float* __restrict__ w_ih,
                          const float* __restrict__ w_hh, const float* __restrict__ w_out,
                          float* __restrict__ out,
                          float* A_base, float* summ,
                          int* last_tok, int* sel_bm, unsigned int* bar) {
  const int bid = blockIdx.x;
  const int tid = threadIdx.x;
  unsigned int ep = 0;

  // ---------------- shared memory (~113KB -> 1 block/CU) ----------------
  __shared__ float sh_xs[32][40];
  __shared__ float sh_hs[32][40];
  __shared__ float sh_ws[6][32][32];
  __shared__ int   sh_toks[32];
  __shared__ int   sh_srow[32];
  __shared__ float sh_h5[KBM][HD];
  __shared__ float sh_part[2][KBM][TT];
  __shared__ float sh_sc5[KBM][TT];
  __shared__ float sh_tmp5[KBM][TT];
  __shared__ float sh_as[32][72];
  __shared__ float sh_bs[64][136];
  __shared__ float sh_candV[KBM * KBM]; __shared__ int sh_candI[KBM * KBM];
  __shared__ int   sh_tokens[KBM][MAXLEN];   // persistent per-batch state (bid<32)
  __shared__ float sh_cum[KBM];
  __shared__ int   sh_fin[KBM]; __shared__ int sh_len[KBM];
  __shared__ float sh_oc[KBM];  __shared__ int sh_ofin[KBM]; __shared__ int sh_olen[KBM];
  __shared__ int   sh_ttmp[KBM * MAXLEN];
  __shared__ int   sh_selI[KBM]; __shared__ float sh_selV[KBM];

  // ---- fence-free tree barrier: 8 spread counters + epoch flag ----
  auto gbar = [&]() {
    asm volatile("s_waitcnt vmcnt(0)" ::: "memory");   // drain outstanding stores
    __syncthreads();
    ep += 1;
    if (tid == 0) {
      __hip_atomic_fetch_add(&bar[(bid & 7) * 32], 1u, __ATOMIC_RELAXED,
                             __HIP_MEMORY_SCOPE_SYSTEM);
      if (bid == 0) {
        for (int c = 0; c < 8; c++) {
          while (__hip_atomic_load(&bar[c * 32], __ATOMIC_RELAXED,
                                   __HIP_MEMORY_SCOPE_SYSTEM) < ep * 32u) {
            __builtin_amdgcn_s_sleep(1);
          }
        }
        __hip_atomic_store(&bar[288], ep, __ATOMIC_RELAXED, __HIP_MEMORY_SCOPE_SYSTEM);
      } else {
        while (__hip_atomic_load(&bar[288], __ATOMIC_RELAXED,
                                 __HIP_MEMORY_SCOPE_SYSTEM) < ep) {
          __builtin_amdgcn_s_sleep(2);
        }
      }
    }
    __syncthreads();
  };

  float* const A_zero = A_base + (size_t)NBUF * NR * 1024;

  // ---------------- init ----------------
  if (bid < BB) {
    if (tid < KBM) { sh_cum[tid] = 0.f; sh_fin[tid] = 0; sh_len[tid] = 0; }
    for (int t = tid; t < KBM * MAXLEN; t += NTHR) sh_tokens[t >> 6][t & 63] = 0;
  }
  {
    int gidx = bid * NTHR + tid;
    v4f z4; z4[0] = z4[1] = z4[2] = z4[3] = 0.f;
    for (int i = gidx; i < NR * 1024 / 4; i += NBLK * NTHR) st4_sys(&A_zero[i * 4], z4);
    for (int t = gidx; t < NR; t += NBLK * NTHR) {
      st_sysi(&last_tok[t], input_var[t / KBM]);
      st_sysi(&sel_bm[t], t % KBM);
    }
  }
  gbar();

  for (int di = 0; di < MAXLEN; di++) {
    float* A_cur = A_base + (size_t)(di & (NBUF - 1)) * NR * 1024;
    const float* A_prev = (di == 0) ? A_zero
                        : A_base + (size_t)((di - 1) & (NBUF - 1)) * NR * 1024;
    // ring wrap: single L1/L2 invalidate so reused buffer addresses refetch
    if (di == NBUF) __builtin_amdgcn_fence(__ATOMIC_ACQUIRE, "agent");

    // ============ GRU (80 blocks: 16 col-tiles x 5 row-tiles, 32x32) ======
    if (bid < 80) {
      const int bx = bid & 15, by = bid >> 4;
      const int i0 = bx * 32, n0 = by * 32;
      const int tx = tid & 31, ty = tid >> 5;    // ty 0..15, 2 rows each
      if (tid < 32) {
        int n = n0 + tid;
        sh_toks[tid] = ld_sysi(&last_tok[n]);
        sh_srow[tid] = (n / KBM) * KBM + ld_sysi(&sel_bm[n]);  // parent-beam gather
      }
      __syncthreads();
      float acc[6][2];
#pragma unroll
      for (int g = 0; g < 6; g++) { acc[g][0] = 0.f; acc[g][1] = 0.f; }
      float hcap0 = 0.f, hcap1 = 0.f;

      auto gru_issue = [&](int k0, v4f& q0, v4f& q1, v4f& q2, v4f& q3) {
        if (tid < 256) {
          int r = tid >> 3, c4 = (tid & 7) * 4;
          q0 = ld4_issue(&emb[(size_t)sh_toks[r] * HD + k0 + c4]);
        } else {
          int r = (tid - 256) >> 3, c4 = ((tid - 256) & 7) * 4;
          q0 = ld4_issue(&A_prev[(size_t)sh_srow[r] * 1024 + k0 + c4]);  // cached!
        }
#pragma unroll
        for (int p = 0; p < 3; p++) {
          int widx = tid + p * 512;
          int g = widx >> 8, rem = widx & 255;
          int kk = rem >> 3, c4 = (rem & 7) * 4;
          const float* W = (g < 3) ? w_ih : w_hh;
          int gc = (g < 3) ? g : g - 3;
          v4f t = ld4_issue(&W[(size_t)(k0 + kk) * 1536 + gc * HD + i0 + c4]);
          if (p == 0) q1 = t; else if (p == 1) q2 = t; else q3 = t;
        }
      };

      v4f c0v, c1v, c2v, c3v, d0v, d1v, d2v, d3v;
      gru_issue(0, c0v, c1v, c2v, c3v);
      for (int k0 = 0; k0 < HD; k0 += 32) {
        vm_bind4(c0v, c1v, c2v, c3v);
        __syncthreads();
        if (tid < 256) {
          int r = tid >> 3, c4 = (tid & 7) * 4;
          *(v4f*)&sh_xs[r][c4] = c0v;
        } else {
          int r = (tid - 256) >> 3, c4 = ((tid - 256) & 7) * 4;
          *(v4f*)&sh_hs[r][c4] = c0v;
        }
#pragma unroll
        for (int p = 0; p < 3; p++) {
          int widx = tid + p * 512;
          int g = widx >> 8, rem = widx & 255;
          int kk = rem >> 3, c4 = (rem & 7) * 4;
          *(v4f*)&sh_ws[g][kk][c4] = (p == 0) ? c1v : (p == 1) ? c2v : c3v;
        }
        if (k0 + 32 < HD) gru_issue(k0 + 32, d0v, d1v, d2v, d3v);  // overlap w/ compute
        __syncthreads();
        if (k0 == i0) {                     // gate h-input from staged tile
          hcap0 = sh_hs[ty * 2 + 0][tx];
          hcap1 = sh_hs[ty * 2 + 1][tx];
        }
#pragma unroll 8
        for (int k = 0; k < 32; k++) {
          float w0 = sh_ws[0][k][tx], w1 = sh_ws[1][k][tx], w2 = sh_ws[2][k][tx];
          float w3 = sh_ws[3][k][tx], w4 = sh_ws[4][k][tx], w5 = sh_ws[5][k][tx];
#pragma unroll
          for (int rr = 0; rr < 2; rr++) {
            float xv = sh_xs[ty * 2 + rr][k];
            float hv = sh_hs[ty * 2 + rr][k];
            acc[0][rr] += xv * w0; acc[1][rr] += xv * w1; acc[2][rr] += xv * w2;
            acc[3][rr] += hv * w3; acc[4][rr] += hv * w4; acc[5][rr] += hv * w5;
          }
        }
        c0v = d0v; c1v = d1v; c2v = d2v; c3v = d3v;
      }
#pragma unroll
      for (int rr = 0; rr < 2; rr++) {
        int n = n0 + ty * 2 + rr, i = i0 + tx;
        float hv = rr ? hcap1 : hcap0;
        float z = 1.f / (1.f + expf(-(acc[0][rr] + acc[3][rr])));
        float r = 1.f / (1.f + expf(-(acc[1][rr] + acc[4][rr])));
        float nn = tanhf(acc[2][rr] + r * acc[5][rr]);
        st_sysf(&A_cur[(size_t)n * 1024 + i], (1.f - z) * nn + z * hv);
      }
    }
    gbar();

    // ============ attention (32 blocks: one per batch) ====================
    if (bid < BB) {
      const int b = bid;
      {
        v4f x0, x1 = {};
        int j0 = tid >> 7, kc0 = (tid & 127) * 4;
        x0 = ld4_issue(&A_cur[(size_t)(b * KBM + j0) * 1024 + kc0]);   // cached
        if (tid < 128) {
          int idx = tid + 512;
          x1 = ld4_issue(&A_cur[(size_t)(b * KBM + (idx >> 7)) * 1024 + (idx & 127) * 4]);
        }
        vm_bind2(x0, x1);
        *(v4f*)&sh_h5[j0][kc0] = x0;
        if (tid < 128) {
          int idx = tid + 512;
          *(v4f*)&sh_h5[idx >> 7][(idx & 127) * 4] = x1;
        }
      }
      __syncthreads();
      {
        const int t = tid & 255, half = tid >> 8;
        const int kb = half * 256;
        float a[KBM];
#pragma unroll
        for (int j = 0; j < KBM; j++) a[j] = 0.f;
        const float* ep2 = enc + ((size_t)b * TT + t) * HD + kb;
#pragma unroll 4
        for (int k = 0; k < 256; k += 4) {
          v4f e = *(const v4f*)(ep2 + k);
#pragma unroll
          for (int j = 0; j < KBM; j++) {
            v4f hj = *(const v4f*)&sh_h5[j][kb + k];
            a[j] += hj[0] * e[0] + hj[1] * e[1] + hj[2] * e[2] + hj[3] * e[3];
          }
        }
#pragma unroll
        for (int j = 0; j < KBM; j++) sh_part[half][j][t] = a[j];
      }
      __syncthreads();
      if (tid < 256) {
#pragma unroll
        for (int j = 0; j < KBM; j++) {
          float sc = (sh_part[0][j][tid] + sh_part[1][j][tid]) * SCALEF;
          sh_sc5[j][tid] = sc;
          sh_tmp5[j][tid] = sc;
        }
      }
      __syncthreads();
      for (int off = 128; off > 0; off >>= 1) {
        if (tid < off) {
#pragma unroll
          for (int j = 0; j < KBM; j++)
            sh_tmp5[j][tid] = fmaxf(sh_tmp5[j][tid], sh_tmp5[j][tid + off]);
        }
        __syncthreads();
      }
      float mj[KBM];
#pragma unroll
      for (int j = 0; j < KBM; j++) mj[j] = sh_tmp5[j][0];
      __syncthreads();
      if (tid < 256) {
#pragma unroll
        for (int j = 0; j < KBM; j++) {
          float e = expf(sh_sc5[j][tid] - mj[j]);
          sh_sc5[j][tid] = e;
          sh_tmp5[j][tid] = e;
        }
      }
      __syncthreads();
      for (int off = 128; off > 0; off >>= 1) {
        if (tid < off) {
#pragma unroll
          for (int j = 0; j < KBM; j++) sh_tmp5[j][tid] += sh_tmp5[j][tid + off];
        }
        __syncthreads();
      }
      float Sj[KBM];
#pragma unroll
      for (int j = 0; j < KBM; j++) Sj[j] = sh_tmp5[j][0];
      __syncthreads();
      if (tid < 256) {
#pragma unroll
        for (int j = 0; j < KBM; j++) sh_sc5[j][tid] = sh_sc5[j][tid] / Sj[j];
      }
      __syncthreads();
      {  // context: thread = column (coalesced enc reads, L2-hot)
        float cx[KBM];
#pragma unroll
        for (int j = 0; j < KBM; j++) cx[j] = 0.f;
        const float* eb = enc + (size_t)b * TT * HD + tid;
#pragma unroll 8
        for (int t2 = 0; t2 < TT; t2++) {
          float e = eb[(size_t)t2 * HD];
#pragma unroll
          for (int j = 0; j < KBM; j++) cx[j] += sh_sc5[j][t2] * e;
        }
#pragma unroll
        for (int j = 0; j < KBM; j++)
          st_sysf(&A_cur[(size_t)(b * KBM + j) * 1024 + HD + tid], cx[j]);
      }
    }
    gbar();

    // ============ output GEMM + fused row summaries (200 blocks) ==========
    if (bid < 200) {
      const int bc = bid % 40, br = bid / 40;
      const int c0 = bc * 128, n0 = br * 32;
      const int tx = tid & 31, ty = tid >> 5;     // ty 0..15, 2 rows each
      float acc[2][4];
#pragma unroll
      for (int rr = 0; rr < 2; rr++)
#pragma unroll
        for (int cc = 0; cc < 4; cc++) acc[rr][cc] = 0.f;

      auto gemm_issue = [&](int k0, v4f& qa, v4f& q0, v4f& q1, v4f& q2, v4f& q3) {
        int ar = tid >> 4, ak4 = (tid & 15) * 4;
        qa = ld4_issue(&A_cur[(size_t)(n0 + ar) * 1024 + k0 + ak4]);   // cached!
#pragma unroll
        for (int p = 0; p < 4; p++) {
          int idx = tid + p * 512;
          int kk = idx >> 5, c4 = (idx & 31) * 4;
          int col = c0 + c4;
          v4f t; t[0] = t[1] = t[2] = t[3] = 0.f;
          if (col + 3 < VV) t = ld4_issue(&w_out[(size_t)(k0 + kk) * VV + col]);
          if (p == 0) q0 = t; else if (p == 1) q1 = t; else if (p == 2) q2 = t; else q3 = t;
        }
      };

      v4f a0, b0, b1, b2, b3, na, nb0, nb1, nb2, nb3;
      gemm_issue(0, a0, b0, b1, b2, b3);
      for (int k0 = 0; k0 < 1024; k0 += 64) {
        vm_bind5(a0, b0, b1, b2, b3);
        __syncthreads();
        {
          int ar = tid >> 4, ak4 = (tid & 15) * 4;
          *(v4f*)&sh_as[ar][ak4] = a0;
        }
#pragma unroll
        for (int p = 0; p < 4; p++) {
          int idx = tid + p * 512;
          int kk = idx >> 5, c4 = (idx & 31) * 4;
          *(v4f*)&sh_bs[kk][c4] = (p == 0) ? b0 : (p == 1) ? b1 : (p == 2) ? b2 : b3;
        }
        if (k0 + 64 < 1024) gemm_issue(k0 + 64, na, nb0, nb1, nb2, nb3);
        __syncthreads();
#pragma unroll 16
        for (int k = 0; k < 64; k++) {
          v4f bv = *(const v4f*)&sh_bs[k][tx * 4];
#pragma unroll
          for (int rr = 0; rr < 2; rr++) {
            float a = sh_as[ty * 2 + rr][k];
            acc[rr][0] += a * bv[0]; acc[rr][1] += a * bv[1];
            acc[rr][2] += a * bv[2]; acc[rr][3] += a * bv[3];
          }
        }
        a0 = na; b0 = nb0; b1 = nb1; b2 = nb2; b3 = nb3;
      }
      // ---- fused epilogue: per-row (m, sumexp, top5) over this tile ----
#pragma unroll
      for (int rr = 0; rr < 2; rr++) {
        const int rowg = n0 + ty * 2 + rr;
        float vv[4]; int ci[4];
        float m = NEGBIG, s = 0.f;
#pragma unroll
        for (int cc = 0; cc < 4; cc++) {
          int c = c0 + tx * 4 + cc;
          ci[cc] = c;
          if (c < VV) {
            float x = acc[rr][cc];
            vv[cc] = x;
            float mn = fmaxf(m, x);
            s = s * expf(m - mn) + expf(x - mn);
            m = mn;
          } else {
            vv[cc] = NEGBIG;
          }
        }
#pragma unroll
        for (int d = 1; d < 32; d <<= 1) {
          float om = __shfl_xor(m, d), os = __shfl_xor(s, d);
          float mm = fmaxf(m, om);
          s = s * expf(m - mm) + os * expf(om - mm);
          m = mm;
        }
        float tv[5]; int ti[5];
#pragma unroll
        for (int q = 0; q < 5; q++) {
          float bvv = vv[0]; int bii = ci[0];
#pragma unroll
          for (int cc = 1; cc < 4; cc++)
            if (viBetter(vv[cc], ci[cc], bvv, bii)) { bvv = vv[cc]; bii = ci[cc]; }
          bfly_argmax<5>(bvv, bii);
          tv[q] = bvv; ti[q] = bii;
#pragma unroll
          for (int cc = 0; cc < 4; cc++)
            if (ci[cc] == bii) vv[cc] = -3.2e38f;
        }
        if ((tid & 31) == 0) {
          float* base = &summ[((size_t)rowg * 40 + bc) * 12];
          v4f p0v, p1v, p2v;
          p0v[0] = m; p0v[1] = s; p0v[2] = tv[0]; p0v[3] = tv[1];
          p1v[0] = tv[2]; p1v[1] = tv[3]; p1v[2] = tv[4];
          p1v[3] = __int_as_float(ti[0]);
          p2v[0] = __int_as_float(ti[1]); p2v[1] = __int_as_float(ti[2]);
          p2v[2] = __int_as_float(ti[3]); p2v[3] = __int_as_float(ti[4]);
          st4_sys(base, p0v); st4_sys(base + 4, p1v); st4_sys(base + 8, p2v);
        }
      }
    }
    gbar();

    // ============ top-k + state update (32 blocks: per batch) =============
    if (bid < BB) {
      const int b = bid;
      if (tid < KBM) {
        sh_oc[tid] = sh_cum[tid]; sh_ofin[tid] = sh_fin[tid]; sh_olen[tid] = sh_len[tid];
      }
      for (int t = tid; t < KBM * MAXLEN; t += NTHR) sh_ttmp[t] = sh_tokens[t >> 6][t & 63];
      __syncthreads();

      const int w = tid >> 6, lane = tid & 63;
      const bool act = (di == 0) ? (w == 0) : (w < KBM);
      if (act) {
        const int j = (di == 0) ? 0 : w;
        if (di > 0 && sh_ofin[j]) {
          if (lane == 0) {
            float cj = sh_oc[j];
            sh_candV[j * KBM + 0] = cj;              // PAD at zero log-prob
            sh_candI[j * KBM + 0] = j * VV + 0;
#pragma unroll
            for (int q = 1; q < KBM; q++) {
              sh_candV[j * KBM + q] = cj + NEGV;
              sh_candI[j * KBM + q] = j * VV + q;
            }
          }
        } else {
          const int row = b * KBM + j;
          float m, s; float lv[5]; int li[5];
          if (lane < 40) {
            const float* base = &summ[((size_t)row * 40 + lane) * 12];
            v4f s0 = ld4_issue_sys(base);
            v4f s1 = ld4_issue_sys(base + 4);
            v4f s2 = ld4_issue_sys(base + 8);
            vm_bind3(s0, s1, s2);
            m = s0[0]; s = s0[1];
            lv[0] = s0[2]; lv[1] = s0[3]; lv[2] = s1[0]; lv[3] = s1[1]; lv[4] = s1[2];
            li[0] = __float_as_int(s1[3]);
            li[1] = __float_as_int(s2[0]); li[2] = __float_as_int(s2[1]);
            li[3] = __float_as_int(s2[2]); li[4] = __float_as_int(s2[3]);
          } else {
            m = NEGBIG; s = 0.f;
#pragma unroll
            for (int q = 0; q < 5; q++) { lv[q] = NEGBIG; li[q] = 0x7fffffff; }
          }
#pragma unroll
          for (int d = 1; d < 64; d <<= 1) {
            float om = __shfl_xor(m, d), os = __shfl_xor(s, d);
            float mm = fmaxf(m, om);
            s = s * expf(m - mm) + os * expf(om - mm);
            m = mm;
          }
          float lse = m + logf(s);
          float cj = (di == 0) ? 0.f : sh_oc[j];
#pragma unroll
          for (int q = 0; q < 5; q++) {
            float bvv = lv[0]; int bii = li[0];
#pragma unroll
            for (int p = 1; p < 5; p++)
              if (viBetter(lv[p], li[p], bvv, bii)) { bvv = lv[p]; bii = li[p]; }
            bfly_argmax<6>(bvv, bii);
            if (lane == 0) {
              sh_candV[j * KBM + q] = cj + (bvv - lse);
              sh_candI[j * KBM + q] = j * VV + bii;
            }
#pragma unroll
            for (int p = 0; p < 5; p++)
              if (li[p] == bii) lv[p] = -3.2e38f;
          }
        }
      }
      __syncthreads();
      if (tid == 0) {
        if (di == 0) {
#pragma unroll
          for (int q = 0; q < KBM; q++) { sh_selV[q] = sh_candV[q]; sh_selI[q] = sh_candI[q]; }
        } else {
          float fv[5]; int fi[5];
#pragma unroll
          for (int q = 0; q < 5; q++) { fv[q] = -INFINITY; fi[q] = 0x7fffffff; }
          for (int t = 0; t < KBM * KBM; t++)
            top5_insert(fv, fi, sh_candV[t], sh_candI[t]);
#pragma unroll
          for (int q = 0; q < 5; q++) { sh_selV[q] = fv[q]; sh_selI[q] = fi[q]; }
        }
      }
      __syncthreads();
      if (tid < KBM) {
        int p = tid, idx = sh_selI[p];
        int bm = idx / VV, tk = idx - bm * VV;
        int pf = sh_ofin[bm];
        sh_cum[p] = sh_selV[p];
        sh_len[p] = sh_olen[bm] + (pf ? 0 : 1);
        sh_fin[p] = (pf || tk == EOSID) ? 1 : 0;
        st_sysi(&last_tok[b * KBM + p], tk);
        st_sysi(&sel_bm[b * KBM + p], bm);   // next-step GRU gathers h via this
      }
      for (int t = tid; t < KBM * MAXLEN; t += NTHR) {
        int p = t >> 6, pos = t & 63;
        int idx = sh_selI[p]; int bm = idx / VV; int tk = idx - bm * VV;
        sh_tokens[p][pos] = (pos == di) ? tk : sh_ttmp[bm * MAXLEN + pos];
      }
    }
    gbar();
  }

  // ================= final: length penalty, best beam, outputs ============
  if (bid < BB) {
    const int b = bid;
    if (tid == 0) {
      int best = 0; float bv = -INFINITY;
#pragma unroll
      for (int jj = 0; jj < KBM; jj++) {
        float c = sh_cum[jj];
        float pen = powf((5.0f + (float)sh_len[jj]) / 6.0f, 1.2f);
        float sel = sh_fin[jj] ? (c / pen) : c;
        if (sel > bv) { bv = sel; best = jj; }
      }
      sh_selI[0] = best;
    }
    __syncthreads();
    if (tid < MAXLEN) out[b * MAXLEN + tid] = (float)sh_tokens[sh_selI[0]][tid];
    if (tid < KBM) out[BB * MAXLEN + b * KBM + tid] = sh_cum[tid];
  }
}

extern "C" void kernel_launch(void* const* d_in, const int* in_sizes, int n_in,
                              void* d_out, int out_size, void* d_ws, size_t ws_size,
                              hipStream_t stream) {
  (void)in_sizes; (void)n_in; (void)out_size; (void)ws_size;
  const int*   input_var = (const int*)d_in[0];
  const float* enc       = (const float*)d_in[1];
  const float* emb       = (const float*)d_in[2];
  const float* w_ih      = (const float*)d_in[3];
  const float* w_hh      = (const float*)d_in[4];
  const float* w_out     = (const float*)d_in[5];
  float* out = (float*)d_out;

  float* A_base   = (float*)d_ws;                              // (NBUF+1)*160*1024
  float* summ     = A_base + (size_t)(NBUF + 1) * NR * 1024;   // 160*40*12
  int*   last_tok = (int*)(summ + (size_t)NR * 40 * 12);       // 160
  int*   sel_bm   = last_tok + NR;                             // 160
  unsigned int* bar = (unsigned int*)(sel_bm + NR);            // 320 uints

  k_zero<<<1, 512, 0, stream>>>(bar);
  k_persist<<<NBLK, NTHR, 0, stream>>>(input_var, enc, emb, w_ih, w_hh, w_out, out,
                                       A_base, summ, last_tok, sel_bm, bar);
}

// Round 9
// 8159.125 us; speedup vs baseline: 1.2829x; 1.2829x over previous
//
#include <hip/hip_runtime.h>
#include <math.h>

// Problem constants
#define BB     32      // batch
#define KBM    5       // beam width
#define NR     160     // BB*KBM rows (beam-major)
#define HD     512     // hidden
#define TT     256     // encoder time steps
#define VV     5000    // vocab
#define MAXLEN 64
#define EOSID  2
#define NEGV   (-1e9f)
#define NEGBIG (-3.0e38f)
#define SCALEF 0.04419417382415922f  // 1/sqrt(512)
#define NBLK   256
#define NTHR   512

typedef float v4f __attribute__((ext_vector_type(4)));

// ---- coherent (L2-bypass) scalar ops for small mutable data ----
__device__ __forceinline__ float ld_sysf(const float* p) {
  return __hip_atomic_load(p, __ATOMIC_RELAXED, __HIP_MEMORY_SCOPE_SYSTEM);
}
__device__ __forceinline__ void st_sysf(float* p, float v) {
  __hip_atomic_store(p, v, __ATOMIC_RELAXED, __HIP_MEMORY_SCOPE_SYSTEM);
}
__device__ __forceinline__ int ld_sysi(const int* p) {
  return __hip_atomic_load(p, __ATOMIC_RELAXED, __HIP_MEMORY_SCOPE_SYSTEM);
}
__device__ __forceinline__ void st_sysi(int* p, int v) {
  __hip_atomic_store(p, v, __ATOMIC_RELAXED, __HIP_MEMORY_SCOPE_SYSTEM);
}

// ---- non-blocking issue + register-bound wait (issue-early / bind-late) ----
// NOTE: issue->bind windows are kept SHORT (no compute between) — a spill of an
// issued-but-unbound destination register is silent garbage (R8 lesson).
__device__ __forceinline__ v4f ld4_issue_sys(const float* p) {   // bypass, coherent
  v4f v;
  asm volatile("global_load_dwordx4 %0, %1, off sc0 sc1" : "=v"(v) : "v"(p));
  return v;
}
__device__ __forceinline__ v4f ld4_issue(const float* p) {       // cached
  v4f v;
  asm volatile("global_load_dwordx4 %0, %1, off" : "=v"(v) : "v"(p));
  return v;
}
__device__ __forceinline__ void vm_bind2(v4f& a, v4f& b) {
  asm volatile("s_waitcnt vmcnt(0)" : "+v"(a), "+v"(b) :: "memory");
}
__device__ __forceinline__ void vm_bind3(v4f& a, v4f& b, v4f& c) {
  asm volatile("s_waitcnt vmcnt(0)" : "+v"(a), "+v"(b), "+v"(c) :: "memory");
}
__device__ __forceinline__ void vm_bind4(v4f& a, v4f& b, v4f& c, v4f& d) {
  asm volatile("s_waitcnt vmcnt(0)" : "+v"(a), "+v"(b), "+v"(c), "+v"(d) :: "memory");
}
__device__ __forceinline__ void vm_bind5(v4f& a, v4f& b, v4f& c, v4f& d, v4f& e) {
  asm volatile("s_waitcnt vmcnt(0)"
               : "+v"(a), "+v"(b), "+v"(c), "+v"(d), "+v"(e) :: "memory");
}
__device__ __forceinline__ void st4_sys(float* p, v4f v) {
  asm volatile("global_store_dwordx4 %0, %1, off sc0 sc1" :: "v"(p), "v"(v) : "memory");
}

// comparator matching jax.lax.top_k stability: value desc, index asc on ties
__device__ __forceinline__ bool viBetter(float av, int ai, float bv, int bi) {
  return (av > bv) || (av == bv && ai < bi);
}

__device__ __forceinline__ void top5_insert(float tv[5], int ti[5], float x, int v) {
  if (!viBetter(x, v, tv[4], ti[4])) return;
  tv[4] = x; ti[4] = v;
#pragma unroll
  for (int q = 4; q > 0; q--) {
    if (viBetter(tv[q], ti[q], tv[q - 1], ti[q - 1])) {
      float tf = tv[q - 1]; int tx2 = ti[q - 1];
      tv[q - 1] = tv[q]; ti[q - 1] = ti[q];
      tv[q] = tf; ti[q] = tx2;
    } else break;
  }
}

template<int LEVELS>
__device__ __forceinline__ void bfly_argmax(float& v, int& i) {
#pragma unroll
  for (int d = 1; d < (1 << LEVELS); d <<= 1) {
    float ov = __shfl_xor(v, d);
    int oi = __shfl_xor(i, d);
    if (viBetter(ov, oi, v, i)) { v = ov; i = oi; }
  }
}

__global__ void k_zero(unsigned int* bar) {
  if (threadIdx.x < 320)
    __hip_atomic_store(&bar[threadIdx.x], 0u, __ATOMIC_RELAXED, __HIP_MEMORY_SCOPE_SYSTEM);
}

__launch_bounds__(NTHR, 1)
__global__ void k_persist(const int* __restrict__ input_var, const float* __restrict__ enc,
                          const float* __restrict__ emb, const float* __restrict__ w_ih,
                          const float* __restrict__ w_hh, const float* __restrict__ w_out,
                          float* __restrict__ out,
                          float* h, float* A_cat, float* summ,
                          int* last_tok, unsigned int* bar) {
  const int bid = blockIdx.x;
  const int tid = threadIdx.x;
  unsigned int ep = 0;

  // ---------------- shared memory (~113KB -> 1 block/CU) ----------------
  __shared__ float sh_xs[32][40];
  __shared__ float sh_hs[32][40];
  __shared__ float sh_ws[6][32][32];
  __shared__ int   sh_toks[32];
  __shared__ float sh_h5[KBM][HD];
  __shared__ float sh_part[2][KBM][TT];
  __shared__ float sh_sc5[KBM][TT];
  __shared__ float sh_tmp5[KBM][TT];
  __shared__ float sh_as[32][72];
  __shared__ float sh_bs[64][136];
  __shared__ float sh_candV[KBM * KBM]; __shared__ int sh_candI[KBM * KBM];
  __shared__ int   sh_tokens[KBM][MAXLEN];   // persistent per-batch state (bid<32)
  __shared__ float sh_cum[KBM];
  __shared__ int   sh_fin[KBM]; __shared__ int sh_len[KBM];
  __shared__ float sh_oc[KBM];  __shared__ int sh_ofin[KBM]; __shared__ int sh_olen[KBM];
  __shared__ int   sh_ttmp[KBM * MAXLEN];
  __shared__ int   sh_selI[KBM]; __shared__ float sh_selV[KBM];

  // ---- fence-free tree barrier: 8 spread counters + epoch flag (R6-proven) ----
  auto gbar = [&]() {
    asm volatile("s_waitcnt vmcnt(0)" ::: "memory");   // drain outstanding stores
    __syncthreads();
    ep += 1;
    if (tid == 0) {
      __hip_atomic_fetch_add(&bar[(bid & 7) * 32], 1u, __ATOMIC_RELAXED,
                             __HIP_MEMORY_SCOPE_SYSTEM);
      if (bid == 0) {
        for (int c = 0; c < 8; c++) {
          while (__hip_atomic_load(&bar[c * 32], __ATOMIC_RELAXED,
                                   __HIP_MEMORY_SCOPE_SYSTEM) < ep * 32u) {
            __builtin_amdgcn_s_sleep(1);
          }
        }
        __hip_atomic_store(&bar[288], ep, __ATOMIC_RELAXED, __HIP_MEMORY_SCOPE_SYSTEM);
      } else {
        while (__hip_atomic_load(&bar[288], __ATOMIC_RELAXED,
                                 __HIP_MEMORY_SCOPE_SYSTEM) < ep) {
          __builtin_amdgcn_s_sleep(2);
        }
      }
    }
    __syncthreads();
  };

  // ---------------- init ----------------
  if (bid < BB) {
    if (tid < KBM) { sh_cum[tid] = 0.f; sh_fin[tid] = 0; sh_len[tid] = 0; }
    for (int t = tid; t < KBM * MAXLEN; t += NTHR) sh_tokens[t >> 6][t & 63] = 0;
  }
  {
    int gidx = bid * NTHR + tid;
    v4f z4; z4[0] = z4[1] = z4[2] = z4[3] = 0.f;
    for (int i = gidx; i < NR * HD / 4; i += NBLK * NTHR) st4_sys(&h[i * 4], z4);
    for (int t = gidx; t < NR; t += NBLK * NTHR) st_sysi(&last_tok[t], input_var[t / KBM]);
  }
  gbar();

  for (int di = 0; di < MAXLEN; di++) {
    // ============ GRU (80 blocks: 16 col-tiles x 5 row-tiles, 32x32) ======
    if (bid < 80) {
      const int bx = bid & 15, by = bid >> 4;
      const int i0 = bx * 32, n0 = by * 32;
      const int tx = tid & 31, ty = tid >> 5;    // ty 0..15, 2 rows each
      if (tid < 32) sh_toks[tid] = ld_sysi(&last_tok[n0 + tid]);
      float acc[6][2];
#pragma unroll
      for (int g = 0; g < 6; g++) { acc[g][0] = 0.f; acc[g][1] = 0.f; }
      float hcap0 = 0.f, hcap1 = 0.f;

      for (int k0 = 0; k0 < HD; k0 += 32) {
        __syncthreads();
        // ---- issue all staging loads, bind once, then LDS-write ----
        v4f v0, v1, v2, v3;
        if (tid < 256) {
          int r = tid >> 3, c4 = (tid & 7) * 4;
          v0 = ld4_issue(&emb[(size_t)sh_toks[r] * HD + k0 + c4]);
        } else {
          int r = (tid - 256) >> 3, c4 = ((tid - 256) & 7) * 4;
          v0 = ld4_issue_sys(&h[(size_t)(n0 + r) * HD + k0 + c4]);
        }
        int gW[3], kW[3], cW[3];
#pragma unroll
        for (int p = 0; p < 3; p++) {
          int widx = tid + p * 512;
          int g = widx >> 8, rem = widx & 255;
          int kk = rem >> 3, c4 = (rem & 7) * 4;
          const float* W = (g < 3) ? w_ih : w_hh;
          int gc = (g < 3) ? g : g - 3;
          v4f t = ld4_issue(&W[(size_t)(k0 + kk) * 1536 + gc * HD + i0 + c4]);
          if (p == 0) v1 = t; else if (p == 1) v2 = t; else v3 = t;
          gW[p] = g; kW[p] = kk; cW[p] = c4;
        }
        vm_bind4(v0, v1, v2, v3);
        if (tid < 256) {
          int r = tid >> 3, c4 = (tid & 7) * 4;
          *(v4f*)&sh_xs[r][c4] = v0;
        } else {
          int r = (tid - 256) >> 3, c4 = ((tid - 256) & 7) * 4;
          *(v4f*)&sh_hs[r][c4] = v0;
        }
        *(v4f*)&sh_ws[gW[0]][kW[0]][cW[0]] = v1;
        *(v4f*)&sh_ws[gW[1]][kW[1]][cW[1]] = v2;
        *(v4f*)&sh_ws[gW[2]][kW[2]][cW[2]] = v3;
        __syncthreads();
        if (k0 == i0) {                     // capture gate h-input from LDS
          hcap0 = sh_hs[ty * 2 + 0][tx];
          hcap1 = sh_hs[ty * 2 + 1][tx];
        }
#pragma unroll 8
        for (int k = 0; k < 32; k++) {
          float w0 = sh_ws[0][k][tx], w1 = sh_ws[1][k][tx], w2 = sh_ws[2][k][tx];
          float w3 = sh_ws[3][k][tx], w4 = sh_ws[4][k][tx], w5 = sh_ws[5][k][tx];
#pragma unroll
          for (int rr = 0; rr < 2; rr++) {
            float xv = sh_xs[ty * 2 + rr][k];
            float hv = sh_hs[ty * 2 + rr][k];
            acc[0][rr] += xv * w0; acc[1][rr] += xv * w1; acc[2][rr] += xv * w2;
            acc[3][rr] += hv * w3; acc[4][rr] += hv * w4; acc[5][rr] += hv * w5;
          }
        }
      }
#pragma unroll
      for (int rr = 0; rr < 2; rr++) {
        int n = n0 + ty * 2 + rr, i = i0 + tx;
        float hv = rr ? hcap1 : hcap0;
        float z = 1.f / (1.f + expf(-(acc[0][rr] + acc[3][rr])));
        float r = 1.f / (1.f + expf(-(acc[1][rr] + acc[4][rr])));
        float nn = tanhf(acc[2][rr] + r * acc[5][rr]);
        st_sysf(&A_cat[(size_t)n * 1024 + i], (1.f - z) * nn + z * hv);
      }
    }
    gbar();

    // ======== phase B: attention (blocks 224..255) CONCURRENT with =========
    // ======== GEMM K-part1 (cols of A = h half, blocks 0..199)     =========
    // GEMM accumulator state lives in registers across the barrier.
    const bool isGemm = (bid < 200);
    const int gbc = bid % 40;
    const int gc0 = gbc * 128, gn0 = (bid / 40) * 32;
    const int gtx = tid & 31, gty = tid >> 5;     // gty 0..15, 2 rows each
    float gacc[2][4];
#pragma unroll
    for (int rr = 0; rr < 2; rr++)
#pragma unroll
      for (int cc = 0; cc < 4; cc++) gacc[rr][cc] = 0.f;

    auto gemm_chunk = [&](int k0) {
      __syncthreads();
      // ---- issue A (bypass) + 4x B (cached), bind once, LDS-write ----
      v4f a0, b0, b1, b2, b3;
      const int ar = tid >> 4, ak4 = (tid & 15) * 4;
      a0 = ld4_issue_sys(&A_cat[(size_t)(gn0 + ar) * 1024 + k0 + ak4]);
      int kkB[4], cB[4];
#pragma unroll
      for (int p = 0; p < 4; p++) {
        int idx = tid + p * 512;
        int kk = idx >> 5, c4 = (idx & 31) * 4;
        int col = gc0 + c4;
        v4f t; t[0] = t[1] = t[2] = t[3] = 0.f;
        if (col + 3 < VV) t = ld4_issue(&w_out[(size_t)(k0 + kk) * VV + col]);
        if (p == 0) b0 = t; else if (p == 1) b1 = t; else if (p == 2) b2 = t; else b3 = t;
        kkB[p] = kk; cB[p] = c4;
      }
      vm_bind5(a0, b0, b1, b2, b3);
      *(v4f*)&sh_as[ar][ak4] = a0;
      *(v4f*)&sh_bs[kkB[0]][cB[0]] = b0;
      *(v4f*)&sh_bs[kkB[1]][cB[1]] = b1;
      *(v4f*)&sh_bs[kkB[2]][cB[2]] = b2;
      *(v4f*)&sh_bs[kkB[3]][cB[3]] = b3;
      __syncthreads();
#pragma unroll 16
      for (int k = 0; k < 64; k++) {
        v4f bv = *(const v4f*)&sh_bs[k][gtx * 4];
#pragma unroll
        for (int rr = 0; rr < 2; rr++) {
          float a = sh_as[gty * 2 + rr][k];
          gacc[rr][0] += a * bv[0]; gacc[rr][1] += a * bv[1];
          gacc[rr][2] += a * bv[2]; gacc[rr][3] += a * bv[3];
        }
      }
    };

    if (isGemm) {
      for (int k0 = 0; k0 < 512; k0 += 64) gemm_chunk(k0);   // h-half of A
    } else if (bid >= 224) {
      // ---------------- attention (one block per batch) ----------------
      const int b = bid - 224;
      {
        v4f x0, x1 = {};
        int j0 = tid >> 7, kc0 = (tid & 127) * 4;
        x0 = ld4_issue_sys(&A_cat[(size_t)(b * KBM + j0) * 1024 + kc0]);
        if (tid < 128) {
          int idx = tid + 512;
          x1 = ld4_issue_sys(&A_cat[(size_t)(b * KBM + (idx >> 7)) * 1024 + (idx & 127) * 4]);
        }
        vm_bind2(x0, x1);
        *(v4f*)&sh_h5[j0][kc0] = x0;
        if (tid < 128) {
          int idx = tid + 512;
          *(v4f*)&sh_h5[idx >> 7][(idx & 127) * 4] = x1;
        }
      }
      __syncthreads();
      {
        const int t = tid & 255, half = tid >> 8;
        const int kb = half * 256;
        float a[KBM];
#pragma unroll
        for (int j = 0; j < KBM; j++) a[j] = 0.f;
        const float* ep2 = enc + ((size_t)b * TT + t) * HD + kb;
#pragma unroll 4
        for (int k = 0; k < 256; k += 4) {
          v4f e = *(const v4f*)(ep2 + k);
#pragma unroll
          for (int j = 0; j < KBM; j++) {
            v4f hj = *(const v4f*)&sh_h5[j][kb + k];
            a[j] += hj[0] * e[0] + hj[1] * e[1] + hj[2] * e[2] + hj[3] * e[3];
          }
        }
#pragma unroll
        for (int j = 0; j < KBM; j++) sh_part[half][j][t] = a[j];
      }
      __syncthreads();
      if (tid < 256) {
#pragma unroll
        for (int j = 0; j < KBM; j++) {
          float sc = (sh_part[0][j][tid] + sh_part[1][j][tid]) * SCALEF;
          sh_sc5[j][tid] = sc;
          sh_tmp5[j][tid] = sc;
        }
      }
      __syncthreads();
      for (int off = 128; off > 0; off >>= 1) {
        if (tid < off) {
#pragma unroll
          for (int j = 0; j < KBM; j++)
            sh_tmp5[j][tid] = fmaxf(sh_tmp5[j][tid], sh_tmp5[j][tid + off]);
        }
        __syncthreads();
      }
      float mj[KBM];
#pragma unroll
      for (int j = 0; j < KBM; j++) mj[j] = sh_tmp5[j][0];
      __syncthreads();
      if (tid < 256) {
#pragma unroll
        for (int j = 0; j < KBM; j++) {
          float e = expf(sh_sc5[j][tid] - mj[j]);
          sh_sc5[j][tid] = e;
          sh_tmp5[j][tid] = e;
        }
      }
      __syncthreads();
      for (int off = 128; off > 0; off >>= 1) {
        if (tid < off) {
#pragma unroll
          for (int j = 0; j < KBM; j++) sh_tmp5[j][tid] += sh_tmp5[j][tid + off];
        }
        __syncthreads();
      }
      float Sj[KBM];
#pragma unroll
      for (int j = 0; j < KBM; j++) Sj[j] = sh_tmp5[j][0];
      __syncthreads();
      if (tid < 256) {
#pragma unroll
        for (int j = 0; j < KBM; j++) sh_sc5[j][tid] = sh_sc5[j][tid] / Sj[j];
      }
      __syncthreads();
      {  // context: thread = column (coalesced enc reads, L2-hot)
        float cx[KBM];
#pragma unroll
        for (int j = 0; j < KBM; j++) cx[j] = 0.f;
        const float* eb = enc + (size_t)b * TT * HD + tid;
#pragma unroll 8
        for (int t2 = 0; t2 < TT; t2++) {
          float e = eb[(size_t)t2 * HD];
#pragma unroll
          for (int j = 0; j < KBM; j++) cx[j] += sh_sc5[j][t2] * e;
        }
#pragma unroll
        for (int j = 0; j < KBM; j++)
          st_sysf(&A_cat[(size_t)(b * KBM + j) * 1024 + HD + tid], cx[j]);
      }
    }
    gbar();

    // ======== phase C: GEMM K-part2 (ctx half) + fused epilogue ===========
    if (isGemm) {
      for (int k0 = 512; k0 < 1024; k0 += 64) gemm_chunk(k0);
      // ---- fused epilogue: per-row (m, sumexp, top5) over this tile ----
#pragma unroll
      for (int rr = 0; rr < 2; rr++) {
        const int rowg = gn0 + gty * 2 + rr;
        float vv[4]; int ci[4];
        float m = NEGBIG, s = 0.f;
#pragma unroll
        for (int cc = 0; cc < 4; cc++) {
          int c = gc0 + gtx * 4 + cc;
          ci[cc] = c;
          if (c < VV) {
            float x = gacc[rr][cc];
            vv[cc] = x;
            float mn = fmaxf(m, x);
            s = s * expf(m - mn) + expf(x - mn);
            m = mn;
          } else {
            vv[cc] = NEGBIG;
          }
        }
        // half-wave (32-lane) lse combine
#pragma unroll
        for (int d = 1; d < 32; d <<= 1) {
          float om = __shfl_xor(m, d), os = __shfl_xor(s, d);
          float mm = fmaxf(m, om);
          s = s * expf(m - mm) + os * expf(om - mm);
          m = mm;
        }
        // 5x extract-max over the 128 cols (32 lanes x 4 each)
        float tv[5]; int ti[5];
#pragma unroll
        for (int q = 0; q < 5; q++) {
          float bvv = vv[0]; int bii = ci[0];
#pragma unroll
          for (int cc = 1; cc < 4; cc++)
            if (viBetter(vv[cc], ci[cc], bvv, bii)) { bvv = vv[cc]; bii = ci[cc]; }
          bfly_argmax<5>(bvv, bii);
          tv[q] = bvv; ti[q] = bii;
#pragma unroll
          for (int cc = 0; cc < 4; cc++)
            if (ci[cc] == bii) vv[cc] = -3.2e38f;
        }
        if ((tid & 31) == 0) {
          float* base = &summ[((size_t)rowg * 40 + gbc) * 12];
          v4f p0v, p1v, p2v;
          p0v[0] = m; p0v[1] = s; p0v[2] = tv[0]; p0v[3] = tv[1];
          p1v[0] = tv[2]; p1v[1] = tv[3]; p1v[2] = tv[4];
          p1v[3] = __int_as_float(ti[0]);
          p2v[0] = __int_as_float(ti[1]); p2v[1] = __int_as_float(ti[2]);
          p2v[2] = __int_as_float(ti[3]); p2v[3] = __int_as_float(ti[4]);
          st4_sys(base, p0v); st4_sys(base + 4, p1v); st4_sys(base + 8, p2v);
        }
      }
    }
    gbar();

    // ============ top-k + state update (32 blocks: per batch) =============
    if (bid < BB) {
      const int b = bid;
      if (tid < KBM) {
        sh_oc[tid] = sh_cum[tid]; sh_ofin[tid] = sh_fin[tid]; sh_olen[tid] = sh_len[tid];
      }
      for (int t = tid; t < KBM * MAXLEN; t += NTHR) sh_ttmp[t] = sh_tokens[t >> 6][t & 63];
      __syncthreads();

      const int w = tid >> 6, lane = tid & 63;
      const bool act = (di == 0) ? (w == 0) : (w < KBM);
      if (act) {
        const int j = (di == 0) ? 0 : w;
        if (di > 0 && sh_ofin[j]) {
          if (lane == 0) {
            float cj = sh_oc[j];
            sh_candV[j * KBM + 0] = cj;              // PAD at zero log-prob
            sh_candI[j * KBM + 0] = j * VV + 0;
#pragma unroll
            for (int q = 1; q < KBM; q++) {
              sh_candV[j * KBM + q] = cj + NEGV;
              sh_candI[j * KBM + q] = j * VV + q;
            }
          }
        } else {
          const int row = b * KBM + j;
          float m, s; float lv[5]; int li[5];
          if (lane < 40) {
            const float* base = &summ[((size_t)row * 40 + lane) * 12];
            v4f s0 = ld4_issue_sys(base);
            v4f s1 = ld4_issue_sys(base + 4);
            v4f s2 = ld4_issue_sys(base + 8);
            vm_bind3(s0, s1, s2);
            m = s0[0]; s = s0[1];
            lv[0] = s0[2]; lv[1] = s0[3]; lv[2] = s1[0]; lv[3] = s1[1]; lv[4] = s1[2];
            li[0] = __float_as_int(s1[3]);
            li[1] = __float_as_int(s2[0]); li[2] = __float_as_int(s2[1]);
            li[3] = __float_as_int(s2[2]); li[4] = __float_as_int(s2[3]);
          } else {
            m = NEGBIG; s = 0.f;
#pragma unroll
            for (int q = 0; q < 5; q++) { lv[q] = NEGBIG; li[q] = 0x7fffffff; }
          }
#pragma unroll
          for (int d = 1; d < 64; d <<= 1) {
            float om = __shfl_xor(m, d), os = __shfl_xor(s, d);
            float mm = fmaxf(m, om);
            s = s * expf(m - mm) + os * expf(om - mm);
            m = mm;
          }
          float lse = m + logf(s);
          float cj = (di == 0) ? 0.f : sh_oc[j];
#pragma unroll
          for (int q = 0; q < 5; q++) {
            float bvv = lv[0]; int bii = li[0];
#pragma unroll
            for (int p = 1; p < 5; p++)
              if (viBetter(lv[p], li[p], bvv, bii)) { bvv = lv[p]; bii = li[p]; }
            bfly_argmax<6>(bvv, bii);
            if (lane == 0) {
              sh_candV[j * KBM + q] = cj + (bvv - lse);
              sh_candI[j * KBM + q] = j * VV + bii;
            }
#pragma unroll
            for (int p = 0; p < 5; p++)
              if (li[p] == bii) lv[p] = -3.2e38f;
          }
        }
      }
      __syncthreads();
      if (tid == 0) {
        if (di == 0) {
#pragma unroll
          for (int q = 0; q < KBM; q++) { sh_selV[q] = sh_candV[q]; sh_selI[q] = sh_candI[q]; }
        } else {
          float fv[5]; int fi[5];
#pragma unroll
          for (int q = 0; q < 5; q++) { fv[q] = -INFINITY; fi[q] = 0x7fffffff; }
          for (int t = 0; t < KBM * KBM; t++)
            top5_insert(fv, fi, sh_candV[t], sh_candI[t]);
#pragma unroll
          for (int q = 0; q < 5; q++) { sh_selV[q] = fv[q]; sh_selI[q] = fi[q]; }
        }
      }
      __syncthreads();
      if (tid < KBM) {
        int p = tid, idx = sh_selI[p];
        int bm = idx / VV, tk = idx - bm * VV;
        int pf = sh_ofin[bm];
        sh_cum[p] = sh_selV[p];
        sh_len[p] = sh_olen[bm] + (pf ? 0 : 1);
        sh_fin[p] = (pf || tk == EOSID) ? 1 : 0;
        st_sysi(&last_tok[b * KBM + p], tk);
      }
      for (int t = tid; t < KBM * MAXLEN; t += NTHR) {
        int p = t >> 6, pos = t & 63;
        int idx = sh_selI[p]; int bm = idx / VV; int tk = idx - bm * VV;
        sh_tokens[p][pos] = (pos == di) ? tk : sh_ttmp[bm * MAXLEN + pos];
      }
      __syncthreads();
      {
        // h <- A_cat[selected beam] (first 512 cols): issue both slots, bind once
        int p0 = tid >> 7, e40 = (tid & 127) * 4;
        int bm0 = sh_selI[p0] / VV;
        v4f y0 = ld4_issue_sys(&A_cat[(size_t)(b * KBM + bm0) * 1024 + e40]);
        v4f y1 = {};
        if (tid < 128) {
          int bm1 = sh_selI[4] / VV;
          y1 = ld4_issue_sys(&A_cat[(size_t)(b * KBM + bm1) * 1024 + tid * 4]);
        }
        vm_bind2(y0, y1);
        st4_sys(&h[(size_t)(b * KBM + p0) * HD + e40], y0);
        if (tid < 128) st4_sys(&h[(size_t)(b * KBM + 4) * HD + tid * 4], y1);
      }
    }
    gbar();
  }

  // ================= final: length penalty, best beam, outputs ============
  if (bid < BB) {
    const int b = bid;
    if (tid == 0) {
      int best = 0; float bv = -INFINITY;
#pragma unroll
      for (int jj = 0; jj < KBM; jj++) {
        float c = sh_cum[jj];
        float pen = powf((5.0f + (float)sh_len[jj]) / 6.0f, 1.2f);
        float sel = sh_fin[jj] ? (c / pen) : c;
        if (sel > bv) { bv = sel; best = jj; }
      }
      sh_selI[0] = best;
    }
    __syncthreads();
    if (tid < MAXLEN) out[b * MAXLEN + tid] = (float)sh_tokens[sh_selI[0]][tid];
    if (tid < KBM) out[BB * MAXLEN + b * KBM + tid] = sh_cum[tid];
  }
}

extern "C" void kernel_launch(void* const* d_in, const int* in_sizes, int n_in,
                              void* d_out, int out_size, void* d_ws, size_t ws_size,
                              hipStream_t stream) {
  (void)in_sizes; (void)n_in; (void)out_size; (void)ws_size;
  const int*   input_var = (const int*)d_in[0];
  const float* enc       = (const float*)d_in[1];
  const float* emb       = (const float*)d_in[2];
  const float* w_ih      = (const float*)d_in[3];
  const float* w_hh      = (const float*)d_in[4];
  const float* w_out     = (const float*)d_in[5];
  float* out = (float*)d_out;

  float* h       = (float*)d_ws;                       // 160*512
  float* A_cat   = h + (size_t)NR * HD;                // 160*1024
  float* summ    = A_cat + (size_t)NR * 1024;          // 160*40*12
  int*   last_tok = (int*)(summ + (size_t)NR * 40 * 12);  // 160
  unsigned int* bar = (unsigned int*)(last_tok + NR);  // 320 uints

  k_zero<<<1, 512, 0, stream>>>(bar);
  k_persist<<<NBLK, NTHR, 0, stream>>>(input_var, enc, emb, w_ih, w_hh, w_out, out,
                                       h, A_cat, summ, last_tok, bar);
}